// Round 7
// baseline (99.727 us; speedup 1.0000x reference)
//
#include <hip/hip_runtime.h>

#define NQ 10
#define TS 10
#define DIM 1024
#define ND 1024
#define NK 8     // 8 float2 pairs = 16 amplitudes per lane

typedef float f2 __attribute__((ext_vector_type(2)));

// ---------- full-rate cross-lane exchange via DPP (no DS pipe) ----------
// row_shr:n -> dst[i] = src[i-n] (0x110|n); row_shl:n -> dst[i] = src[i+n] (0x100|n)
template<int CTRL>
__device__ __forceinline__ float dpp_full(float x) {
    const int xi = __float_as_int(x);
    return __int_as_float(__builtin_amdgcn_update_dpp(xi, xi, CTRL, 0xF, 0xF, false));
}
__device__ __forceinline__ float dpp_xor4(float x) {
    const int xi = __float_as_int(x);
    // banks 0,2 (bit2=0) need src[i+4] -> row_shl:4 (0x104), bank_mask 0x5
    // banks 1,3 (bit2=1) need src[i-4] -> row_shr:4 (0x114), bank_mask 0xA
    int q = __builtin_amdgcn_update_dpp(0, xi, 0x104, 0xF, 0x5, false);
    q     = __builtin_amdgcn_update_dpp(q, xi, 0x114, 0xF, 0xA, false);
    return __int_as_float(q);
}
template<int MASK>
__device__ __forceinline__ float lshuf(float x) {
    if constexpr (MASK == 1)      return dpp_full<0xB1>(x);   // quad_perm [1,0,3,2]
    else if constexpr (MASK == 2) return dpp_full<0x4E>(x);   // quad_perm [2,3,0,1]
    else if constexpr (MASK == 4) return dpp_xor4(x);
    else                          return dpp_full<0x128>(x);  // row_ror:8 == xor8
}

// ---------- gfx950 permlane swaps: full-rate VALU cross-register row swaps ----
// v_permlane32_swap_b32 a,b : a'=[a.lo,b.lo], b'=[a.hi,b.hi]  (self-inverse)
// v_permlane16_swap_b32 a,b : a'=[a.r0,b.r0,a.r2,b.r2], b'=[a.r1,b.r1,a.r3,b.r3]
__device__ __forceinline__ void swap32(float& a, float& b) {
    asm("v_permlane32_swap_b32 %0, %1" : "+v"(a), "+v"(b));
}
__device__ __forceinline__ void swap16(float& a, float& b) {
    asm("v_permlane16_swap_b32 %0, %1" : "+v"(a), "+v"(b));
}

// ---------- gates (M00=(A,-B) M01=(-C,-D) M10=(C,-D) M11=(A,B)) ----------
template <int RB>
__device__ __forceinline__ void gate_k(f2* PR, f2* PI,
                                       float A, float B, float C, float D) {
#pragma unroll
    for (int k0 = 0; k0 < NK; ++k0) {
        if (k0 & (1 << RB)) continue;
        const int k1 = k0 | (1 << RB);
        const f2 x0r = PR[k0], x0i = PI[k0];
        const f2 x1r = PR[k1], x1i = PI[k1];
        PR[k0] = A * x0r + B * x0i - C * x1r + D * x1i;
        PI[k0] = A * x0i - B * x0r - C * x1i - D * x1r;
        PR[k1] = C * x0r + D * x0i + A * x1r - B * x1i;
        PI[k1] = C * x0i - D * x0r + A * x1i + B * x1r;
    }
}

__device__ __forceinline__ void gate_j(f2* PR, f2* PI,
                                       float A, float B, float C, float D) {
    const f2 AC   = {A, C},  BD  = {B, D};
    const f2 mCA  = {-C, A}, DmB = {D, -B};
    const f2 mBmD = {-B, -D}, mDB = {-D, B};
#pragma unroll
    for (int k = 0; k < NK; ++k) {
        const f2 rx = PR[k].xx, ry = PR[k].yy;
        const f2 ix = PI[k].xx, iy = PI[k].yy;
        PR[k] = AC * rx + BD * ix + mCA * ry + DmB * iy;
        PI[k] = AC * ix + mBmD * rx + mCA * iy + mDB * ry;
    }
}

// xor16 / xor32 lane gates via permlane swap: swap-in converts lane pairing
// into same-lane cross-register pairing (x0 = bit=0 member, x1 = bit=1 member),
// uniform 2x2 math, swap-out (self-inverse) restores layout. Zero DS ops.
template <int WHICH>   // 16 or 32
__device__ __forceinline__ void gate_swap(f2* PR, f2* PI,
                                          float A, float B, float C, float D) {
#pragma unroll
    for (int k = 0; k < NK; ++k) {
        float x0r = PR[k].x, x1r = PR[k].y;
        float x0i = PI[k].x, x1i = PI[k].y;
        if constexpr (WHICH == 32) { swap32(x0r, x1r); swap32(x0i, x1i); }
        else                       { swap16(x0r, x1r); swap16(x0i, x1i); }
        float n0r = A * x0r + B * x0i - C * x1r + D * x1i;
        float n0i = A * x0i - B * x0r - C * x1i - D * x1r;
        float n1r = C * x0r + D * x0i + A * x1r - B * x1i;
        float n1i = C * x0i - D * x0r + A * x1i + B * x1r;
        if constexpr (WHICH == 32) { swap32(n0r, n1r); swap32(n0i, n1i); }
        else                       { swap16(n0r, n1r); swap16(n0i, n1i); }
        PR[k] = (f2){n0r, n1r};
        PI[k] = (f2){n0i, n1i};
    }
}

template <int MASK>    // 1,2,4,8 via DPP
__device__ __forceinline__ void gate_lane(int lane, f2* PR, f2* PI,
                                          float A, float B, float C, float D) {
    const float sgn = (lane & MASK) ? 1.f : -1.f;
    const float ownI  = sgn * B;   // own coeff  = (A, ownI)
    const float partR = sgn * C;   // part coeff = (partR, -D)
    f2 qR[NK], qI[NK];
#pragma unroll
    for (int k = 0; k < NK; ++k) {
        qR[k].x = lshuf<MASK>(PR[k].x);
        qR[k].y = lshuf<MASK>(PR[k].y);
        qI[k].x = lshuf<MASK>(PI[k].x);
        qI[k].y = lshuf<MASK>(PI[k].y);
    }
#pragma unroll
    for (int k = 0; k < NK; ++k) {
        const f2 orr = PR[k], oi = PI[k];
        PR[k] = A * orr - ownI * oi + partR * qR[k] + D * qI[k];
        PI[k] = A * oi + ownI * orr + partR * qI[k] - D * qR[k];
    }
}

// One wave per sample, full state in registers, zero LDS, ZERO DS in main loop.
__global__ __launch_bounds__(64, 1) void qsim_kernel(
    const float* __restrict__ re_in, const float* __restrict__ im_in,
    const float* __restrict__ phis, const float* __restrict__ gs,
    float* __restrict__ out)
{
    const int sample = blockIdx.x;
    const int lane = threadIdx.x;

    const float* pr_in = re_in + sample * DIM;
    const float* pi_in = im_in + sample * DIM;

    f2 PR[NK], PI[NK];
#pragma unroll
    for (int k = 0; k < NK; ++k) {
        PR[k].x = pr_in[(2 * k) * 64 + lane];
        PR[k].y = pr_in[(2 * k + 1) * 64 + lane];
        PI[k].x = pi_in[(2 * k) * 64 + lane];
        PI[k].y = pi_in[(2 * k + 1) * 64 + lane];
    }

    const float inv = 0.15811388300841897f;  // 1/(2*sqrt(10))
    float gl[TS];
#pragma unroll
    for (int t = 0; t < TS; ++t) gl[t] = gs[sample * TS + t] * inv;

    // ---- normalize ----
    f2 n2 = {0.f, 0.f};
#pragma unroll
    for (int k = 0; k < NK; ++k) n2 += PR[k] * PR[k] + PI[k] * PI[k];
    float nrm = n2.x + n2.y;
#pragma unroll
    for (int off = 32; off >= 1; off >>= 1) nrm += __shfl_xor(nrm, off, 64);
    const float scl = rsqrtf(nrm);
#pragma unroll
    for (int k = 0; k < NK; ++k) { PR[k] *= scl; PI[k] *= scl; }

    // ---- pairsum per amplitude ----
    f2 PS[NK];
#pragma unroll
    for (int k = 0; k < NK; ++k) {
        const int i0 = (2 * k) * 64 + lane;
        const int i1 = (2 * k + 1) * 64 + lane;
        const int z0 = NQ - 2 * __popc(i0);
        const int z1 = NQ - 2 * __popc(i1);
        PS[k].x = 0.5f * (float)(z0 * z0 - NQ);
        PS[k].y = 0.5f * (float)(z1 * z1 - NQ);
    }

    const float* ph = phis + sample * (3 * NQ * TS);

    for (int tt = 0; tt < TS; ++tt) {
        float phs[30];
#pragma unroll
        for (int j = 0; j < 30; ++j) phs[j] = ph[30 * tt + j];

        // ---- all transcendentals for this step, hoisted & independent ----
        float GA[NQ], GB[NQ], GC[NQ], GD[NQ];
#pragma unroll
        for (int g = 0; g < NQ; ++g) {
            const float a = phs[g], th = phs[10 + g], b = phs[20 + g];
            float c, s, cp, sp, cm, sm;
            __sincosf(0.5f * th,      &s,  &c);
            __sincosf(0.5f * (a + b), &sp, &cp);
            __sincosf(0.5f * (a - b), &sm, &cm);
            GA[g] = c * cp; GB[g] = c * sp; GC[g] = s * cm; GD[g] = s * sm;
        }
        f2 DC[NK], DS_[NK];
        const float kk = -0.5f * gl[tt];
#pragma unroll
        for (int k = 0; k < NK; ++k) {
            float sx, cx, sy, cy;
            __sincosf(kk * PS[k].x, &sx, &cx);
            __sincosf(kk * PS[k].y, &sy, &cy);
            DC[k]  = (f2){cx, cy};
            DS_[k] = (f2){sx, sy};
        }

        // ---- gates ----
        gate_k<2>(PR, PI, GA[0], GB[0], GC[0], GD[0]);            // qubit 0 (bit 9)
        gate_k<1>(PR, PI, GA[1], GB[1], GC[1], GD[1]);            // qubit 1 (bit 8)
        gate_k<0>(PR, PI, GA[2], GB[2], GC[2], GD[2]);            // qubit 2 (bit 7)
        gate_j   (PR, PI, GA[3], GB[3], GC[3], GD[3]);            // qubit 3 (bit 6)
        gate_swap<32>(PR, PI, GA[4], GB[4], GC[4], GD[4]);        // qubit 4 (permlane32)
        gate_swap<16>(PR, PI, GA[5], GB[5], GC[5], GD[5]);        // qubit 5 (permlane16)
        gate_lane< 8>(lane, PR, PI, GA[6], GB[6], GC[6], GD[6]);  // qubit 6 (DPP)
        gate_lane< 4>(lane, PR, PI, GA[7], GB[7], GC[7], GD[7]);  // qubit 7 (DPP)
        gate_lane< 2>(lane, PR, PI, GA[8], GB[8], GC[8], GD[8]);  // qubit 8 (DPP)
        gate_lane< 1>(lane, PR, PI, GA[9], GB[9], GC[9], GD[9]);  // qubit 9 (DPP)

        // ---- diagonal phase ----
#pragma unroll
        for (int k = 0; k < NK; ++k) {
            const f2 xr = PR[k], xi = PI[k];
            PR[k] = xr * DC[k] - xi * DS_[k];
            PI[k] = xr * DS_[k] + xi * DC[k];
        }
    }

    float* outr = out + sample * DIM;
    float* outi = out + ND * DIM + sample * DIM;
#pragma unroll
    for (int k = 0; k < NK; ++k) {
        outr[(2 * k) * 64 + lane]     = PR[k].x;
        outr[(2 * k + 1) * 64 + lane] = PR[k].y;
        outi[(2 * k) * 64 + lane]     = PI[k].x;
        outi[(2 * k + 1) * 64 + lane] = PI[k].y;
    }
}

extern "C" void kernel_launch(void* const* d_in, const int* in_sizes, int n_in,
                              void* d_out, int out_size, void* d_ws, size_t ws_size,
                              hipStream_t stream) {
    const float* re_in = (const float*)d_in[0];
    const float* im_in = (const float*)d_in[1];
    const float* phis  = (const float*)d_in[2];
    const float* gs    = (const float*)d_in[3];
    float* out = (float*)d_out;
    qsim_kernel<<<ND, 64, 0, stream>>>(re_in, im_in, phis, gs, out);
}

// Round 8
// 97.763 us; speedup vs baseline: 1.0201x; 1.0201x over previous
//
#include <hip/hip_runtime.h>

#define NQ 10
#define TS 10
#define DIM 1024
#define ND 1024
#define NR 16    // 16 complex amplitudes per lane

typedef float f2 __attribute__((ext_vector_type(2)));  // (re, im)

// ---------- full-rate cross-lane exchange via DPP ----------
// row_shr:n -> dst[i]=src[i-n] (0x110|n); row_shl:n -> dst[i]=src[i+n] (0x100|n)
template<int CTRL>
__device__ __forceinline__ float dpp_full(float x) {
    const int xi = __float_as_int(x);
    return __int_as_float(__builtin_amdgcn_update_dpp(xi, xi, CTRL, 0xF, 0xF, false));
}
__device__ __forceinline__ float dpp_xor4(float x) {
    const int xi = __float_as_int(x);
    // banks 0,2 (bit2=0) need src[i+4] -> row_shl:4 (0x104), bank_mask 0x5
    // banks 1,3 (bit2=1) need src[i-4] -> row_shr:4 (0x114), bank_mask 0xA
    int q = __builtin_amdgcn_update_dpp(0, xi, 0x104, 0xF, 0x5, false);
    q     = __builtin_amdgcn_update_dpp(q, xi, 0x114, 0xF, 0xA, false);
    return __int_as_float(q);
}
template<int MASK>
__device__ __forceinline__ float lshuf(float x) {
    if constexpr (MASK == 1)      return dpp_full<0xB1>(x);   // quad_perm [1,0,3,2]
    else if constexpr (MASK == 2) return dpp_full<0x4E>(x);   // quad_perm [2,3,0,1]
    else if constexpr (MASK == 4) return dpp_xor4(x);
    else if constexpr (MASK == 8) return dpp_full<0x128>(x);  // row_ror:8 == xor8
    else return __shfl_xor(x, MASK, 64);                      // 16,32: ds_bpermute
}
template<int MASK>
__device__ __forceinline__ f2 xchg(f2 v) {
    return (f2){lshuf<MASK>(v.x), lshuf<MASK>(v.y)};
}

// ---------- gates (M00=(A,-B) M01=(-C,-D) M10=(C,-D) M11=(A,B)) ----------
// In-thread pairing on register bit RB. 8 pk-fma-chains per pair.
template <int RB>
__device__ __forceinline__ void gate_r(f2* S, float A, float B, float C, float D) {
    const f2 AA = {A, A}, BN = {B, -B}, NB = {-B, B};
    const f2 CC = {C, C}, NC = {-C, -C}, DN = {D, -D};
#pragma unroll
    for (int r0 = 0; r0 < NR; ++r0) {
        if (r0 & (1 << RB)) continue;
        const int r1 = r0 | (1 << RB);
        const f2 x0 = S[r0], x1 = S[r1];
        const f2 x0s = x0.yx, x1s = x1.yx;
        S[r0] = AA * x0 + BN * x0s + NC * x1 + DN * x1s;
        S[r1] = CC * x0 + DN * x0s + AA * x1 + NB * x1s;
    }
}

// Cross-lane pairing on lane bit MASK. own coeff (A, sgn*B), part (sgn*C, -D).
template <int MASK>
__device__ __forceinline__ void gate_lane(int lane, f2* S,
                                          float A, float B, float C, float D) {
    const float sgn = (lane & MASK) ? 1.f : -1.f;
    const float sB = sgn * B, sC = sgn * C;
    const f2 AA = {A, A}, SB = {-sB, sB}, SC = {sC, sC}, DN = {D, -D};
    f2 q[NR];
#pragma unroll
    for (int r = 0; r < NR; ++r) q[r] = xchg<MASK>(S[r]);   // batch exchanges
#pragma unroll
    for (int r = 0; r < NR; ++r) {
        const f2 o = S[r];
        S[r] = AA * o + SB * o.yx + SC * q[r] + DN * q[r].yx;
    }
}

// One wave per sample, full state in registers, zero LDS.
__global__ __launch_bounds__(64, 1) void qsim_kernel(
    const float* __restrict__ re_in, const float* __restrict__ im_in,
    const float* __restrict__ phis, const float* __restrict__ gs,
    float* __restrict__ out)
{
    const int sample = blockIdx.x;
    const int lane = threadIdx.x;

    const float* pr_in = re_in + sample * DIM;
    const float* pi_in = im_in + sample * DIM;

    f2 S[NR];
#pragma unroll
    for (int r = 0; r < NR; ++r) {
        S[r].x = pr_in[r * 64 + lane];
        S[r].y = pi_in[r * 64 + lane];
    }

    const float inv = 0.15811388300841897f;  // 1/(2*sqrt(10))
    float gl[TS];
#pragma unroll
    for (int t = 0; t < TS; ++t) gl[t] = gs[sample * TS + t] * inv;

    // ---- normalize ----
    f2 n2 = {0.f, 0.f};
#pragma unroll
    for (int r = 0; r < NR; ++r) n2 += S[r] * S[r];
    float nrm = n2.x + n2.y;
#pragma unroll
    for (int off = 32; off >= 1; off >>= 1) nrm += __shfl_xor(nrm, off, 64);
    const float scl = rsqrtf(nrm);
#pragma unroll
    for (int r = 0; r < NR; ++r) S[r] *= scl;

    // ---- pairsum per amplitude ----
    float ps[NR];
#pragma unroll
    for (int r = 0; r < NR; ++r) {
        const int idx = r * 64 + lane;
        const int z = NQ - 2 * __popc(idx);
        ps[r] = 0.5f * (float)(z * z - NQ);
    }

    const float* ph = phis + sample * (3 * NQ * TS);

    for (int tt = 0; tt < TS; ++tt) {
        float phs[30];
#pragma unroll
        for (int j = 0; j < 30; ++j) phs[j] = ph[30 * tt + j];

        // ---- all transcendentals for this step, hoisted & independent ----
        float GA[NQ], GB[NQ], GC[NQ], GD[NQ];
#pragma unroll
        for (int g = 0; g < NQ; ++g) {
            const float a = phs[g], th = phs[10 + g], b = phs[20 + g];
            float c, s, cp, sp, cm, sm;
            __sincosf(0.5f * th,      &s,  &c);
            __sincosf(0.5f * (a + b), &sp, &cp);
            __sincosf(0.5f * (a - b), &sm, &cm);
            GA[g] = c * cp; GB[g] = c * sp; GC[g] = s * cm; GD[g] = s * sm;
        }
        f2 EC[NR], ES[NR];
        const float kk = -0.5f * gl[tt];
#pragma unroll
        for (int r = 0; r < NR; ++r) {
            float sa, ca;
            __sincosf(kk * ps[r], &sa, &ca);
            EC[r] = (f2){ca, ca};
            ES[r] = (f2){-sa, sa};
        }

        // ---- gates: qubit q acts on idx bit (9-q) ----
        gate_r<3>(S, GA[0], GB[0], GC[0], GD[0]);                 // qubit 0 (bit 9)
        gate_r<2>(S, GA[1], GB[1], GC[1], GD[1]);                 // qubit 1 (bit 8)
        gate_r<1>(S, GA[2], GB[2], GC[2], GD[2]);                 // qubit 2 (bit 7)
        gate_r<0>(S, GA[3], GB[3], GC[3], GD[3]);                 // qubit 3 (bit 6)
        gate_lane<32>(lane, S, GA[4], GB[4], GC[4], GD[4]);       // qubit 4 (shfl)
        gate_lane<16>(lane, S, GA[5], GB[5], GC[5], GD[5]);       // qubit 5 (shfl)
        gate_lane< 8>(lane, S, GA[6], GB[6], GC[6], GD[6]);       // qubit 6 (DPP)
        gate_lane< 4>(lane, S, GA[7], GB[7], GC[7], GD[7]);       // qubit 7 (DPP)
        gate_lane< 2>(lane, S, GA[8], GB[8], GC[8], GD[8]);       // qubit 8 (DPP)
        gate_lane< 1>(lane, S, GA[9], GB[9], GC[9], GD[9]);       // qubit 9 (DPP)

        // ---- diagonal phase: x = e * x (complex) ----
#pragma unroll
        for (int r = 0; r < NR; ++r) {
            S[r] = EC[r] * S[r] + ES[r] * S[r].yx;
        }
    }

    float* outr = out + sample * DIM;
    float* outi = out + ND * DIM + sample * DIM;
#pragma unroll
    for (int r = 0; r < NR; ++r) {
        outr[r * 64 + lane] = S[r].x;
        outi[r * 64 + lane] = S[r].y;
    }
}

extern "C" void kernel_launch(void* const* d_in, const int* in_sizes, int n_in,
                              void* d_out, int out_size, void* d_ws, size_t ws_size,
                              hipStream_t stream) {
    const float* re_in = (const float*)d_in[0];
    const float* im_in = (const float*)d_in[1];
    const float* phis  = (const float*)d_in[2];
    const float* gs    = (const float*)d_in[3];
    float* out = (float*)d_out;
    qsim_kernel<<<ND, 64, 0, stream>>>(re_in, im_in, phis, gs, out);
}